// Round 7
// baseline (333.933 us; speedup 1.0000x reference)
//
#include <hip/hip_runtime.h>
#include <hip/hip_fp16.h>

#define HID 32
#define LEAKY 0.01f
#define SE3NORM 0.17677669529663687f   // 1/sqrt(32)
#define SCAN_TILE 1024                 // elements per scan block (256 thr x 4)
#define NBK 128                        // nodes per fine (dst) bucket
#define GA 128                         // pass-A blocks
#define RR 4                           // src ranges (phasing)

// ======================= two-level bucket CSR build, key = (srcRange, dst) =======================

__device__ __forceinline__ int src_range(int s, unsigned magic) {
    int r = (int)__umulhi((unsigned)s, magic);
    return r < RR - 1 ? r : RR - 1;
}

// pass A1: per-block LDS histogram of coarse bucket; bh[b2*GA + g] = count
__global__ void k_bhist(const int* __restrict__ ei, int* __restrict__ bh,
                        int E, int B1, int B2, int chunk, unsigned magic) {
    extern __shared__ int lh[];                 // B2 ints
    int g = blockIdx.x;
    for (int i = threadIdx.x; i < B2; i += 256) lh[i] = 0;
    __syncthreads();
    int beg = g * chunk, end = min(E, beg + chunk);
    for (int e = beg + (int)threadIdx.x; e < end; e += 256) {
        int s = ei[e];
        int d = ei[E + e];
        atomicAdd(&lh[src_range(s, magic) * B1 + (d >> 7)], 1);
    }
    __syncthreads();
    for (int b = threadIdx.x; b < B2; b += 256) bh[b * GA + g] = lh[b];
}

// scan pass 1: per-tile exclusive scan IN PLACE + tile sums
__global__ void k_scan1(int* __restrict__ data, int* __restrict__ bsum, int M) {
    __shared__ int lds[256];
    int t = threadIdx.x;
    int base = blockIdx.x * SCAN_TILE + t * 4;
    int v0 = (base + 0 < M) ? data[base + 0] : 0;
    int v1 = (base + 1 < M) ? data[base + 1] : 0;
    int v2 = (base + 2 < M) ? data[base + 2] : 0;
    int v3 = (base + 3 < M) ? data[base + 3] : 0;
    int s = v0 + v1 + v2 + v3;
    lds[t] = s;
    __syncthreads();
    for (int off = 1; off < 256; off <<= 1) {
        int x = (t >= off) ? lds[t - off] : 0;
        __syncthreads();
        lds[t] += x;
        __syncthreads();
    }
    int ex = lds[t] - s;
    if (base + 0 < M) data[base + 0] = ex;
    if (base + 1 < M) data[base + 1] = ex + v0;
    if (base + 2 < M) data[base + 2] = ex + v0 + v1;
    if (base + 3 < M) data[base + 3] = ex + v0 + v1 + v2;
    if (t == 255) bsum[blockIdx.x] = lds[255];
}

// scan pass 2: exclusive scan of tile sums in place (single block, B <= 1024)
__global__ void k_scan2(int* __restrict__ bsum, int B) {
    __shared__ int lds[256];
    int t = threadIdx.x;
    int base = t * 4;
    int v0 = (base + 0 < B) ? bsum[base + 0] : 0;
    int v1 = (base + 1 < B) ? bsum[base + 1] : 0;
    int v2 = (base + 2 < B) ? bsum[base + 2] : 0;
    int v3 = (base + 3 < B) ? bsum[base + 3] : 0;
    int s = v0 + v1 + v2 + v3;
    lds[t] = s;
    __syncthreads();
    for (int off = 1; off < 256; off <<= 1) {
        int x = (t >= off) ? lds[t - off] : 0;
        __syncthreads();
        lds[t] += x;
        __syncthreads();
    }
    int ex = lds[t] - s;
    if (base + 0 < B) bsum[base + 0] = ex;
    if (base + 1 < B) bsum[base + 1] = ex + v0;
    if (base + 2 < B) bsum[base + 2] = ex + v0 + v1;
    if (base + 3 < B) bsum[base + 3] = ex + v0 + v1 + v2;
}

// scan pass 3: add tile prefix in place; optionally init cursor copy
__global__ void k_scan3(int* __restrict__ data, const int* __restrict__ bsum,
                        int* __restrict__ cursor, int M, int N) {
    int i = blockIdx.x * blockDim.x + threadIdx.x;
    if (i >= M) return;
    int off = data[i] + bsum[i / SCAN_TILE];
    data[i] = off;
    if (cursor && i < N) cursor[i] = off;
}

// pass A3: scatter edges into coarse buckets via LDS cursors; pack (localdst<<24)|src
__global__ void k_bscatter(const int* __restrict__ ei, const int* __restrict__ bh,
                           int* __restrict__ bucketed, int E, int B1, int B2,
                           int chunk, unsigned magic) {
    extern __shared__ int cur[];                // B2 ints
    int g = blockIdx.x;
    for (int b = threadIdx.x; b < B2; b += 256) cur[b] = bh[b * GA + g];
    __syncthreads();
    int beg = g * chunk, end = min(E, beg + chunk);
    for (int e = beg + (int)threadIdx.x; e < end; e += 256) {
        int s = ei[e];
        int d = ei[E + e];
        int b = src_range(s, magic) * B1 + (d >> 7);
        int p = atomicAdd(&cur[b], 1);          // LDS atomic; slices disjoint per (b,g)
        bucketed[p] = s | ((d & (NBK - 1)) << 24);
    }
}

// pass B: per-bucket LDS counting sort by localdst -> sorted_src + offsets[r*N + dst]
__global__ void k_bsort(const int* __restrict__ bh, const int* __restrict__ bucketed,
                        int* __restrict__ sorted_src, int* __restrict__ offsets,
                        int E, int N, int B1, int B2) {
    __shared__ int hist[NBK], sc[NBK], base[NBK];
    int b2 = blockIdx.x;
    int r  = b2 / B1;
    int cb = b2 - r * B1;
    int t = threadIdx.x;
    int bs = bh[b2 * GA];
    int be = (b2 == B2 - 1) ? E : bh[(b2 + 1) * GA];
    if (t < NBK) hist[t] = 0;
    __syncthreads();
    for (int e = bs + t; e < be; e += 256)
        atomicAdd(&hist[bucketed[e] >> 24], 1);
    __syncthreads();
    int v = (t < NBK) ? hist[t] : 0;
    if (t < NBK) sc[t] = v;
    __syncthreads();
    for (int off = 1; off < NBK; off <<= 1) {
        int x = (t < NBK && t >= off) ? sc[t - off] : 0;
        __syncthreads();
        if (t < NBK) sc[t] += x;
        __syncthreads();
    }
    if (t < NBK) base[t] = sc[t] - v;
    __syncthreads();
    if (t < NBK) hist[t] = base[t];             // reuse as cursor
    __syncthreads();
    for (int e = bs + t; e < be; e += 256) {
        int pv = bucketed[e];
        int p = atomicAdd(&hist[pv >> 24], 1);
        sorted_src[bs + p] = pv & 0x00FFFFFF;
    }
    int node = cb * NBK + t;
    if (t < NBK && node < N) offsets[(size_t)r * N + node] = bs + base[t];
    if (b2 == B2 - 1 && t == 0) offsets[(size_t)RR * N] = E;
}

// ======================= fallback CSR build (global atomics, R4 path) =======================
__global__ void k_hist_rank(const int* __restrict__ ei, int* __restrict__ hist,
                            int* __restrict__ rank, int E) {
    int base = (blockIdx.x * blockDim.x + threadIdx.x) * 4;
#pragma unroll
    for (int u = 0; u < 4; u++) {
        int e = base + u;
        if (e < E) rank[e] = atomicAdd(&hist[ei[E + e]], 1);
    }
}
__global__ void k_scatter_rank(const int* __restrict__ ei, const int* __restrict__ offsets,
                               const int* __restrict__ rank, int* __restrict__ sorted_src, int E) {
    int base = (blockIdx.x * blockDim.x + threadIdx.x) * 4;
#pragma unroll
    for (int u = 0; u < 4; u++) {
        int e = base + u;
        if (e < E) sorted_src[offsets[ei[E + e]] + rank[e]] = ei[e];
    }
}

// ======================= node-level kernels =======================
// layer 1: agg1 over Rr segments + h1 = leaky(agg1@Wl1+bl1+x@Wr1)@Wse1*SE3NORM -> fp16
__global__ void k_node1(const int* __restrict__ offsets, const int* __restrict__ sorted_src,
                        const float* __restrict__ pos,
                        const float* __restrict__ Wl1, const float* __restrict__ bl1,
                        const float* __restrict__ Wr1, const float* __restrict__ Wse1,
                        __half* __restrict__ h1out, int N, int Rr) {
    __shared__ float sWl1[2 * HID], sWr1[2 * HID], sbl1[HID], sWse1[HID * HID];
    for (int i = threadIdx.x; i < 2 * HID; i += blockDim.x) { sWl1[i] = Wl1[i]; sWr1[i] = Wr1[i]; }
    for (int i = threadIdx.x; i < HID; i += blockDim.x) sbl1[i] = bl1[i];
    for (int i = threadIdx.x; i < HID * HID; i += blockDim.x) sWse1[i] = Wse1[i];
    __syncthreads();
    int i = blockIdx.x * blockDim.x + threadIdx.x;
    if (i >= N) return;
    float a0 = 0.f, a1 = 0.f;
    for (int r = 0; r < Rr; r++) {
        int beg = offsets[(size_t)r * N + i], end = offsets[(size_t)r * N + i + 1];
        int e = beg;
        for (; e + 4 <= end; e += 4) {
            int s0 = sorted_src[e], s1 = sorted_src[e + 1], s2 = sorted_src[e + 2], s3 = sorted_src[e + 3];
            a0 += pos[s0 * 3] + pos[s1 * 3] + pos[s2 * 3] + pos[s3 * 3];
            a1 += pos[s0 * 3 + 1] + pos[s1 * 3 + 1] + pos[s2 * 3 + 1] + pos[s3 * 3 + 1];
        }
        for (; e < end; e++) {
            int s = sorted_src[e];
            a0 += pos[s * 3];
            a1 += pos[s * 3 + 1];
        }
    }
    float x0 = pos[3 * i], x1 = pos[3 * i + 1];
    float h[HID];
#pragma unroll
    for (int j = 0; j < HID; j++) {
        float v = a0 * sWl1[j] + a1 * sWl1[HID + j] + sbl1[j] + x0 * sWr1[j] + x1 * sWr1[HID + j];
        h[j] = v > 0.f ? v : LEAKY * v;
    }
    union Pack8 { __half h[8]; float4 v; };
#pragma unroll
    for (int c = 0; c < HID / 8; c++) {
        Pack8 p;
#pragma unroll
        for (int jj = 0; jj < 8; jj++) {
            int j = c * 8 + jj;
            float acc = 0.f;
#pragma unroll
            for (int k = 0; k < HID; k++) acc += h[k] * sWse1[k * HID + j];
            p.h[jj] = __float2half(acc * SE3NORM);
        }
        *(float4*)&h1out[(size_t)i * HID + c * 8] = p.v;
    }
}

// phased layer-2 aggregation: agg2[dst] (+)= sum of h1[src] over range-r segment
__global__ void k_node2agg(const int* __restrict__ offsets, const int* __restrict__ sorted_src,
                           const __half* __restrict__ h1, float* __restrict__ agg2,
                           int N, int r) {
    int lt = blockIdx.x * blockDim.x + threadIdx.x;
    int node = lt >> 3;
    int t = lt & 7;
    if (node >= N) return;
    int beg = offsets[(size_t)r * N + node], end = offsets[(size_t)r * N + node + 1];
    float4 acc;
    if (r == 0) acc = make_float4(0.f, 0.f, 0.f, 0.f);
    else        acc = *(const float4*)&agg2[(size_t)node * HID + t * 4];
    int e = beg;
    for (; e + 4 <= end; e += 4) {
        int s0 = sorted_src[e], s1 = sorted_src[e + 1];
        int s2 = sorted_src[e + 2], s3 = sorted_src[e + 3];
        float2 r0 = *(const float2*)&h1[(size_t)s0 * HID + t * 4];
        float2 r1 = *(const float2*)&h1[(size_t)s1 * HID + t * 4];
        float2 r2 = *(const float2*)&h1[(size_t)s2 * HID + t * 4];
        float2 r3 = *(const float2*)&h1[(size_t)s3 * HID + t * 4];
        const float2* rs[4] = {&r0, &r1, &r2, &r3};
#pragma unroll
        for (int u = 0; u < 4; u++) {
            __half2 p01 = *(const __half2*)&rs[u]->x;
            __half2 p23 = *(const __half2*)&rs[u]->y;
            acc.x += __low2float(p01); acc.y += __high2float(p01);
            acc.z += __low2float(p23); acc.w += __high2float(p23);
        }
    }
    for (; e < end; e++) {
        int s = sorted_src[e];
        float2 rr = *(const float2*)&h1[(size_t)s * HID + t * 4];
        __half2 p01 = *(const __half2*)&rr.x;
        __half2 p23 = *(const __half2*)&rr.y;
        acc.x += __low2float(p01); acc.y += __high2float(p01);
        acc.z += __low2float(p23); acc.w += __high2float(p23);
    }
    *(float4*)&agg2[(size_t)node * HID + t * 4] = acc;
}

// head: conv2 from agg2 + skip + MLP -> out (8 lanes/node, LDS staged)
__global__ void k_node2head(const float* __restrict__ agg2, const __half* __restrict__ h1,
                            const float* __restrict__ Wl2, const float* __restrict__ bl2,
                            const float* __restrict__ Wr2, const float* __restrict__ Wse2,
                            const float* __restrict__ W3, const float* __restrict__ b3,
                            const float* __restrict__ W4, const float* __restrict__ b4,
                            const float* __restrict__ alpha_p,
                            float* __restrict__ out, int N) {
    __shared__ float sWl2[HID * HID], sWr2[HID * HID], sWse2[HID * HID], sW3[HID * HID];
    __shared__ float sbl2[HID], sb3[HID], sW4[HID];
    __shared__ float sb4, salpha;
    __shared__ float sA[32][HID + 1], sB[32][HID + 1];
    for (int i = threadIdx.x; i < HID * HID; i += blockDim.x) {
        sWl2[i] = Wl2[i]; sWr2[i] = Wr2[i]; sWse2[i] = Wse2[i]; sW3[i] = W3[i];
    }
    for (int i = threadIdx.x; i < HID; i += blockDim.x) { sbl2[i] = bl2[i]; sb3[i] = b3[i]; sW4[i] = W4[i]; }
    if (threadIdx.x == 0) { sb4 = b4[0]; salpha = alpha_p[0]; }
    __syncthreads();

    const int lt = threadIdx.x;
    const int nodeL = lt >> 3;
    const int t = lt & 7;
    const int node = blockIdx.x * 32 + nodeL;
    const bool live = node < N;

    float hvr[4];
    if (live) {
        float4 a = *(const float4*)&agg2[(size_t)node * HID + t * 4];
        float2 ro = *(const float2*)&h1[(size_t)node * HID + t * 4];
        __half2 o01 = *(const __half2*)&ro.x;
        __half2 o23 = *(const __half2*)&ro.y;
        hvr[0] = __low2float(o01); hvr[1] = __high2float(o01);
        hvr[2] = __low2float(o23); hvr[3] = __high2float(o23);
        sA[nodeL][t * 4 + 0] = a.x; sA[nodeL][t * 4 + 1] = a.y;
        sA[nodeL][t * 4 + 2] = a.z; sA[nodeL][t * 4 + 3] = a.w;
        sB[nodeL][t * 4 + 0] = hvr[0]; sB[nodeL][t * 4 + 1] = hvr[1];
        sB[nodeL][t * 4 + 2] = hvr[2]; sB[nodeL][t * 4 + 3] = hvr[3];
    }
    __syncthreads();

    float h2r[4];
    if (live) {
#pragma unroll
        for (int jj = 0; jj < 4; jj++) {
            int j = t * 4 + jj;
            float acc = sbl2[j];
#pragma unroll
            for (int k = 0; k < HID; k++)
                acc += sA[nodeL][k] * sWl2[k * HID + j] + sB[nodeL][k] * sWr2[k * HID + j];
            h2r[jj] = acc > 0.f ? acc : LEAKY * acc;
        }
    }
    __syncthreads();
    if (live) {
#pragma unroll
        for (int jj = 0; jj < 4; jj++) sA[nodeL][t * 4 + jj] = h2r[jj];
    }
    __syncthreads();

    if (live) {
#pragma unroll
        for (int jj = 0; jj < 4; jj++) {
            int j = t * 4 + jj;
            float acc = 0.f;
#pragma unroll
            for (int k = 0; k < HID; k++) acc += sA[nodeL][k] * sWse2[k * HID + j];
            sB[nodeL][j] = salpha * hvr[jj] + acc * SE3NORM;
        }
    }
    __syncthreads();

    float part = 0.f;
#pragma unroll
    for (int jj = 0; jj < 4; jj++) {
        int j = t * 4 + jj;
        float acc = sb3[j];
        if (live) {
#pragma unroll
            for (int k = 0; k < HID; k++) acc += sB[nodeL][k] * sW3[k * HID + j];
        }
        part += (acc > 0.f ? acc : 0.f) * sW4[j];
    }
    part += __shfl_xor(part, 1);
    part += __shfl_xor(part, 2);
    part += __shfl_xor(part, 4);
    if (live && t == 0) out[node] = part + sb4;
}

// fallback direct-gather layer2+head (R6 path)
__global__ void k_node2out(const int* __restrict__ offsets, const int* __restrict__ sorted_src,
                           const __half* __restrict__ h1,
                           const float* __restrict__ Wl2, const float* __restrict__ bl2,
                           const float* __restrict__ Wr2, const float* __restrict__ Wse2,
                           const float* __restrict__ W3, const float* __restrict__ b3,
                           const float* __restrict__ W4, const float* __restrict__ b4,
                           const float* __restrict__ alpha_p,
                           float* __restrict__ out, int N) {
    __shared__ float sWl2[HID * HID], sWr2[HID * HID], sWse2[HID * HID], sW3[HID * HID];
    __shared__ float sbl2[HID], sb3[HID], sW4[HID];
    __shared__ float sb4, salpha;
    __shared__ float sA[32][HID + 1], sB[32][HID + 1];
    for (int i = threadIdx.x; i < HID * HID; i += blockDim.x) {
        sWl2[i] = Wl2[i]; sWr2[i] = Wr2[i]; sWse2[i] = Wse2[i]; sW3[i] = W3[i];
    }
    for (int i = threadIdx.x; i < HID; i += blockDim.x) { sbl2[i] = bl2[i]; sb3[i] = b3[i]; sW4[i] = W4[i]; }
    if (threadIdx.x == 0) { sb4 = b4[0]; salpha = alpha_p[0]; }
    __syncthreads();
    const int lt = threadIdx.x;
    const int nodeL = lt >> 3;
    const int t = lt & 7;
    const int node = blockIdx.x * 32 + nodeL;
    const bool live = node < N;
    float hvr[4];
    if (live) {
        int beg = offsets[node], end = offsets[node + 1];
        float4 acc = make_float4(0.f, 0.f, 0.f, 0.f);
        for (int e = beg; e < end; e++) {
            int s = sorted_src[e];
            float2 rr = *(const float2*)&h1[(size_t)s * HID + t * 4];
            __half2 p01 = *(const __half2*)&rr.x;
            __half2 p23 = *(const __half2*)&rr.y;
            acc.x += __low2float(p01); acc.y += __high2float(p01);
            acc.z += __low2float(p23); acc.w += __high2float(p23);
        }
        float2 ro = *(const float2*)&h1[(size_t)node * HID + t * 4];
        __half2 o01 = *(const __half2*)&ro.x;
        __half2 o23 = *(const __half2*)&ro.y;
        hvr[0] = __low2float(o01); hvr[1] = __high2float(o01);
        hvr[2] = __low2float(o23); hvr[3] = __high2float(o23);
        sA[nodeL][t * 4 + 0] = acc.x; sA[nodeL][t * 4 + 1] = acc.y;
        sA[nodeL][t * 4 + 2] = acc.z; sA[nodeL][t * 4 + 3] = acc.w;
        sB[nodeL][t * 4 + 0] = hvr[0]; sB[nodeL][t * 4 + 1] = hvr[1];
        sB[nodeL][t * 4 + 2] = hvr[2]; sB[nodeL][t * 4 + 3] = hvr[3];
    }
    __syncthreads();
    float h2r[4];
    if (live) {
#pragma unroll
        for (int jj = 0; jj < 4; jj++) {
            int j = t * 4 + jj;
            float acc = sbl2[j];
#pragma unroll
            for (int k = 0; k < HID; k++)
                acc += sA[nodeL][k] * sWl2[k * HID + j] + sB[nodeL][k] * sWr2[k * HID + j];
            h2r[jj] = acc > 0.f ? acc : LEAKY * acc;
        }
    }
    __syncthreads();
    if (live) {
#pragma unroll
        for (int jj = 0; jj < 4; jj++) sA[nodeL][t * 4 + jj] = h2r[jj];
    }
    __syncthreads();
    if (live) {
#pragma unroll
        for (int jj = 0; jj < 4; jj++) {
            int j = t * 4 + jj;
            float acc = 0.f;
#pragma unroll
            for (int k = 0; k < HID; k++) acc += sA[nodeL][k] * sWse2[k * HID + j];
            sB[nodeL][j] = salpha * hvr[jj] + acc * SE3NORM;
        }
    }
    __syncthreads();
    float part = 0.f;
#pragma unroll
    for (int jj = 0; jj < 4; jj++) {
        int j = t * 4 + jj;
        float acc = sb3[j];
        if (live) {
#pragma unroll
            for (int k = 0; k < HID; k++) acc += sB[nodeL][k] * sW3[k * HID + j];
        }
        part += (acc > 0.f ? acc : 0.f) * sW4[j];
    }
    part += __shfl_xor(part, 1);
    part += __shfl_xor(part, 2);
    part += __shfl_xor(part, 4);
    if (live && t == 0) out[node] = part + sb4;
}

extern "C" void kernel_launch(void* const* d_in, const int* in_sizes, int n_in,
                              void* d_out, int out_size, void* d_ws, size_t ws_size,
                              hipStream_t stream) {
    const float* pos  = (const float*)d_in[0];
    const int*   ei   = (const int*)d_in[1];
    const float* Wl1  = (const float*)d_in[2];
    const float* bl1  = (const float*)d_in[3];
    const float* Wr1  = (const float*)d_in[4];
    const float* Wl2  = (const float*)d_in[5];
    const float* bl2  = (const float*)d_in[6];
    const float* Wr2  = (const float*)d_in[7];
    const float* Wse1 = (const float*)d_in[8];
    const float* Wse2 = (const float*)d_in[9];
    const float* W3   = (const float*)d_in[10];
    const float* b3   = (const float*)d_in[11];
    const float* W4   = (const float*)d_in[12];
    const float* b4   = (const float*)d_in[13];
    const float* alp  = (const float*)d_in[14];
    float* out = (float*)d_out;

    const int N = in_sizes[0] / 3;
    const int E = in_sizes[1] / 2;
    const int blk = 256;
    const size_t h1bytes = (size_t)N * HID * sizeof(__half);

    // ---- phased bucket path ----
    const int B1 = (N + NBK - 1) / NBK;        // dst coarse buckets per range
    const int B2 = RR * B1;                    // total coarse buckets
    const int M2 = B2 * GA;
    const int S2 = (M2 + SCAN_TILE - 1) / SCAN_TILE;
    const int rangeSize = (N + RR - 1) / RR;
    const unsigned magic = (unsigned)(((1ULL << 32) + rangeSize - 1) / rangeSize);
    {
        int* bh         = (int*)d_ws;
        int* bsum       = bh + M2;
        int* region     = bsum + 1024;                     // bucketed[E] then agg2[N*HID] (aliased)
        size_t regionInts = (size_t)E > (size_t)N * HID ? (size_t)E : (size_t)N * HID;
        int* sorted_src = region + regionInts;
        int* offsets    = sorted_src + E;                  // RR*N + 1
        uintptr_t hp = ((uintptr_t)(offsets + (size_t)RR * N + 1) + 15) & ~(uintptr_t)15;
        size_t need = (hp - (uintptr_t)d_ws) + h1bytes;
        if (need <= ws_size && S2 <= 1024) {
            int* bucketed = region;
            float* agg2   = (float*)region;
            __half* h1 = (__half*)hp;
            const int chunk = (E + GA - 1) / GA;
            const size_t ldsB = (size_t)B2 * sizeof(int);
            k_bhist<<<GA, 256, ldsB, stream>>>(ei, bh, E, B1, B2, chunk, magic);
            k_scan1<<<S2, 256, 0, stream>>>(bh, bsum, M2);
            k_scan2<<<1, 256, 0, stream>>>(bsum, S2);
            k_scan3<<<(M2 + blk - 1) / blk, blk, 0, stream>>>(bh, bsum, nullptr, M2, 0);
            k_bscatter<<<GA, 256, ldsB, stream>>>(ei, bh, bucketed, E, B1, B2, chunk, magic);
            k_bsort<<<B2, 256, 0, stream>>>(bh, bucketed, sorted_src, offsets, E, N, B1, B2);
            k_node1<<<(N + blk - 1) / blk, blk, 0, stream>>>(offsets, sorted_src, pos,
                                                             Wl1, bl1, Wr1, Wse1, h1, N, RR);
            const int agrid = ((N * 8) + blk - 1) / blk;
            for (int r = 0; r < RR; r++)
                k_node2agg<<<agrid, blk, 0, stream>>>(offsets, sorted_src, h1, agg2, N, r);
            k_node2head<<<(N + 31) / 32, 256, 0, stream>>>(agg2, h1, Wl2, bl2, Wr2, Wse2,
                                                           W3, b3, W4, b4, alp, out, N);
            return;
        }
    }

    // ---- fallback: global-atomic CSR build + direct gather ----
    const int M = N + 1;
    const int B = (M + SCAN_TILE - 1) / SCAN_TILE;
    int* hist       = (int*)d_ws;
    int* bsum       = hist + M;
    int* sorted_src = bsum + 1024;
    int* aux        = sorted_src + E;          // rank[E]
    uintptr_t hpA = ((uintptr_t)(aux + E) + 15) & ~(uintptr_t)15;
    __half* h1 = (__half*)hpA;

    hipMemsetAsync(hist, 0, (size_t)M * sizeof(int), stream);
    const int egrid4 = (E / 4 + blk) / blk;
    k_hist_rank<<<egrid4, blk, 0, stream>>>(ei, hist, aux, E);
    k_scan1<<<B, 256, 0, stream>>>(hist, bsum, M);
    k_scan2<<<1, 256, 0, stream>>>(bsum, B);
    k_scan3<<<(M + blk - 1) / blk, blk, 0, stream>>>(hist, bsum, nullptr, M, N);
    int* offs = hist;
    k_scatter_rank<<<egrid4, blk, 0, stream>>>(ei, offs, aux, sorted_src, E);
    k_node1<<<(N + blk - 1) / blk, blk, 0, stream>>>(offs, sorted_src, pos, Wl1, bl1, Wr1, Wse1, h1, N, 1);
    k_node2out<<<(N + 31) / 32, 256, 0, stream>>>(offs, sorted_src, h1, Wl2, bl2, Wr2, Wse2,
                                                  W3, b3, W4, b4, alp, out, N);
}

// Round 8
// 307.370 us; speedup vs baseline: 1.0864x; 1.0864x over previous
//
#include <hip/hip_runtime.h>
#include <hip/hip_fp16.h>

#define HID 32
#define LEAKY 0.01f
#define SE3NORM 0.17677669529663687f   // 1/sqrt(32)
#define SCAN_TILE 1024                 // elements per scan block (256 thr x 4)
#define NBK 128                        // dst nodes per coarse bucket
#define GA 256                         // pass-A blocks
#define RR 4                           // src ranges (phasing)

__device__ __forceinline__ int src_range(int s, unsigned magic) {
    int r = (int)__umulhi((unsigned)s, magic);
    return r < RR - 1 ? r : RR - 1;
}

// ======================= CSR build: coarse dst buckets, fine 512-bin sort =======================

// pass A1: per-block LDS histogram of coarse bucket (dst>>7); bh[b*GA + g] = count
__global__ void k_bhist(const int* __restrict__ ei, int* __restrict__ bh,
                        int E, int B1, int chunk) {
    extern __shared__ int lh[];                 // B1 ints
    int g = blockIdx.x;
    for (int i = threadIdx.x; i < B1; i += 256) lh[i] = 0;
    __syncthreads();
    int beg = g * chunk, end = min(E, beg + chunk);
    for (int e = beg + (int)threadIdx.x; e < end; e += 256)
        atomicAdd(&lh[ei[E + e] >> 7], 1);
    __syncthreads();
    for (int b = threadIdx.x; b < B1; b += 256) bh[b * GA + g] = lh[b];
}

// scan pass 1: per-tile exclusive scan IN PLACE + tile sums
__global__ void k_scan1(int* __restrict__ data, int* __restrict__ bsum, int M) {
    __shared__ int lds[256];
    int t = threadIdx.x;
    int base = blockIdx.x * SCAN_TILE + t * 4;
    int v0 = (base + 0 < M) ? data[base + 0] : 0;
    int v1 = (base + 1 < M) ? data[base + 1] : 0;
    int v2 = (base + 2 < M) ? data[base + 2] : 0;
    int v3 = (base + 3 < M) ? data[base + 3] : 0;
    int s = v0 + v1 + v2 + v3;
    lds[t] = s;
    __syncthreads();
    for (int off = 1; off < 256; off <<= 1) {
        int x = (t >= off) ? lds[t - off] : 0;
        __syncthreads();
        lds[t] += x;
        __syncthreads();
    }
    int ex = lds[t] - s;
    if (base + 0 < M) data[base + 0] = ex;
    if (base + 1 < M) data[base + 1] = ex + v0;
    if (base + 2 < M) data[base + 2] = ex + v0 + v1;
    if (base + 3 < M) data[base + 3] = ex + v0 + v1 + v2;
    if (t == 255) bsum[blockIdx.x] = lds[255];
}

// scan pass 2: exclusive scan of tile sums in place (single block, B <= 1024)
__global__ void k_scan2(int* __restrict__ bsum, int B) {
    __shared__ int lds[256];
    int t = threadIdx.x;
    int base = t * 4;
    int v0 = (base + 0 < B) ? bsum[base + 0] : 0;
    int v1 = (base + 1 < B) ? bsum[base + 1] : 0;
    int v2 = (base + 2 < B) ? bsum[base + 2] : 0;
    int v3 = (base + 3 < B) ? bsum[base + 3] : 0;
    int s = v0 + v1 + v2 + v3;
    lds[t] = s;
    __syncthreads();
    for (int off = 1; off < 256; off <<= 1) {
        int x = (t >= off) ? lds[t - off] : 0;
        __syncthreads();
        lds[t] += x;
        __syncthreads();
    }
    int ex = lds[t] - s;
    if (base + 0 < B) bsum[base + 0] = ex;
    if (base + 1 < B) bsum[base + 1] = ex + v0;
    if (base + 2 < B) bsum[base + 2] = ex + v0 + v1;
    if (base + 3 < B) bsum[base + 3] = ex + v0 + v1 + v2;
}

// scan pass 3: add tile prefix in place; optionally init cursor copy
__global__ void k_scan3(int* __restrict__ data, const int* __restrict__ bsum,
                        int* __restrict__ cursor, int M, int N) {
    int i = blockIdx.x * blockDim.x + threadIdx.x;
    if (i >= M) return;
    int off = data[i] + bsum[i / SCAN_TILE];
    data[i] = off;
    if (cursor && i < N) cursor[i] = off;
}

// pass A3: scatter edges into coarse buckets via LDS cursors; pack (localdst<<24)|src
__global__ void k_bscatter(const int* __restrict__ ei, const int* __restrict__ bh,
                           int* __restrict__ bucketed, int E, int B1, int chunk) {
    extern __shared__ int cur[];                // B1 ints
    int g = blockIdx.x;
    for (int b = threadIdx.x; b < B1; b += 256) cur[b] = bh[b * GA + g];
    __syncthreads();
    int beg = g * chunk, end = min(E, beg + chunk);
    for (int e = beg + (int)threadIdx.x; e < end; e += 256) {
        int d = ei[E + e];
        int s = ei[e];
        int b = d >> 7;
        int p = atomicAdd(&cur[b], 1);          // LDS atomic; slices disjoint per (b,g)
        bucketed[p] = s | ((d & (NBK - 1)) << 24);
    }
}

// pass B: per-bucket 512-bin counting sort, bin = (localdst<<2)|srcRange
//         -> sorted_src + node-major off2[node*4 + r]
__global__ void k_bsort(const int* __restrict__ bh, const int* __restrict__ bucketed,
                        int* __restrict__ sorted_src, int* __restrict__ off2,
                        int E, int N, int B1, unsigned magic) {
    __shared__ int hist[512], base[512];
    __shared__ int lds[256];
    int b = blockIdx.x;
    int t = threadIdx.x;
    int bs = bh[b * GA];
    int be = (b == B1 - 1) ? E : bh[(b + 1) * GA];
    hist[t] = 0; hist[t + 256] = 0;
    __syncthreads();
    for (int e = bs + t; e < be; e += 256) {
        int pv = bucketed[e];
        int bin = ((pv >> 24) << 2) | src_range(pv & 0x00FFFFFF, magic);
        atomicAdd(&hist[bin], 1);
    }
    __syncthreads();
    int v0 = hist[2 * t], v1 = hist[2 * t + 1];
    int s = v0 + v1;
    lds[t] = s;
    __syncthreads();
    for (int off = 1; off < 256; off <<= 1) {
        int x = (t >= off) ? lds[t - off] : 0;
        __syncthreads();
        lds[t] += x;
        __syncthreads();
    }
    int ex = lds[t] - s;
    base[2 * t] = ex; base[2 * t + 1] = ex + v0;
    __syncthreads();
    hist[t] = base[t]; hist[t + 256] = base[t + 256];   // cursors
    __syncthreads();
    for (int e = bs + t; e < be; e += 256) {
        int pv = bucketed[e];
        int bin = ((pv >> 24) << 2) | src_range(pv & 0x00FFFFFF, magic);
        int p = atomicAdd(&hist[bin], 1);
        sorted_src[bs + p] = pv & 0x00FFFFFF;
    }
#pragma unroll
    for (int u = 0; u < 2; u++) {
        int bin = t + u * 256;
        int node = b * NBK + (bin >> 2);
        if (node < N) off2[node * 4 + (bin & 3)] = bs + base[bin];
    }
    if (b == B1 - 1 && t == 0) off2[4 * N] = E;
}

// ======================= fallback CSR build (global atomics) =======================
__global__ void k_hist_rank(const int* __restrict__ ei, int* __restrict__ hist,
                            int* __restrict__ rank, int E) {
    int base = (blockIdx.x * blockDim.x + threadIdx.x) * 4;
#pragma unroll
    for (int u = 0; u < 4; u++) {
        int e = base + u;
        if (e < E) rank[e] = atomicAdd(&hist[ei[E + e]], 1);
    }
}
__global__ void k_scatter_rank(const int* __restrict__ ei, const int* __restrict__ offsets,
                               const int* __restrict__ rank, int* __restrict__ sorted_src, int E) {
    int base = (blockIdx.x * blockDim.x + threadIdx.x) * 4;
#pragma unroll
    for (int u = 0; u < 4; u++) {
        int e = base + u;
        if (e < E) sorted_src[offsets[ei[E + e]] + rank[e]] = ei[e];
    }
}

// ======================= node-level kernels =======================
// layer 1: agg1 segment sum (stride-S offsets, span W) + h1 MLP -> fp16
__global__ void k_node1(const int* __restrict__ offsets, const int* __restrict__ sorted_src,
                        const float* __restrict__ pos,
                        const float* __restrict__ Wl1, const float* __restrict__ bl1,
                        const float* __restrict__ Wr1, const float* __restrict__ Wse1,
                        __half* __restrict__ h1out, int N, int S, int W) {
    __shared__ float sWl1[2 * HID], sWr1[2 * HID], sbl1[HID], sWse1[HID * HID];
    for (int i = threadIdx.x; i < 2 * HID; i += blockDim.x) { sWl1[i] = Wl1[i]; sWr1[i] = Wr1[i]; }
    for (int i = threadIdx.x; i < HID; i += blockDim.x) sbl1[i] = bl1[i];
    for (int i = threadIdx.x; i < HID * HID; i += blockDim.x) sWse1[i] = Wse1[i];
    __syncthreads();
    int i = blockIdx.x * blockDim.x + threadIdx.x;
    if (i >= N) return;
    int beg = offsets[(size_t)i * S], end = offsets[(size_t)i * S + W];
    float a0 = 0.f, a1 = 0.f;
    int e = beg;
    for (; e + 4 <= end; e += 4) {
        int s0 = sorted_src[e], s1 = sorted_src[e + 1], s2 = sorted_src[e + 2], s3 = sorted_src[e + 3];
        a0 += pos[s0 * 3] + pos[s1 * 3] + pos[s2 * 3] + pos[s3 * 3];
        a1 += pos[s0 * 3 + 1] + pos[s1 * 3 + 1] + pos[s2 * 3 + 1] + pos[s3 * 3 + 1];
    }
    for (; e < end; e++) {
        int s = sorted_src[e];
        a0 += pos[s * 3];
        a1 += pos[s * 3 + 1];
    }
    float x0 = pos[3 * i], x1 = pos[3 * i + 1];
    float h[HID];
#pragma unroll
    for (int j = 0; j < HID; j++) {
        float v = a0 * sWl1[j] + a1 * sWl1[HID + j] + sbl1[j] + x0 * sWr1[j] + x1 * sWr1[HID + j];
        h[j] = v > 0.f ? v : LEAKY * v;
    }
    union Pack8 { __half h[8]; float4 v; };
#pragma unroll
    for (int c = 0; c < HID / 8; c++) {
        Pack8 p;
#pragma unroll
        for (int jj = 0; jj < 8; jj++) {
            int j = c * 8 + jj;
            float acc = 0.f;
#pragma unroll
            for (int k = 0; k < HID; k++) acc += h[k] * sWse1[k * HID + j];
            p.h[jj] = __float2half(acc * SE3NORM);
        }
        *(float4*)&h1out[(size_t)i * HID + c * 8] = p.v;
    }
}

// phased layer-2 aggregation: agg2[dst] (+)= sum of h1[src] over range-r sub-segment
__global__ void k_node2agg(const int* __restrict__ off2, const int* __restrict__ sorted_src,
                           const __half* __restrict__ h1, float* __restrict__ agg2,
                           int N, int r) {
    int lt = blockIdx.x * blockDim.x + threadIdx.x;
    int node = lt >> 3;
    int t = lt & 7;
    if (node >= N) return;
    int beg = off2[(size_t)node * 4 + r], end = off2[(size_t)node * 4 + r + 1];
    float4 acc;
    if (r == 0) acc = make_float4(0.f, 0.f, 0.f, 0.f);
    else        acc = *(const float4*)&agg2[(size_t)node * HID + t * 4];
    int e = beg;
    for (; e + 4 <= end; e += 4) {
        int s0 = sorted_src[e], s1 = sorted_src[e + 1];
        int s2 = sorted_src[e + 2], s3 = sorted_src[e + 3];
        float2 r0 = *(const float2*)&h1[(size_t)s0 * HID + t * 4];
        float2 r1 = *(const float2*)&h1[(size_t)s1 * HID + t * 4];
        float2 r2 = *(const float2*)&h1[(size_t)s2 * HID + t * 4];
        float2 r3 = *(const float2*)&h1[(size_t)s3 * HID + t * 4];
        const float2* rs[4] = {&r0, &r1, &r2, &r3};
#pragma unroll
        for (int u = 0; u < 4; u++) {
            __half2 p01 = *(const __half2*)&rs[u]->x;
            __half2 p23 = *(const __half2*)&rs[u]->y;
            acc.x += __low2float(p01); acc.y += __high2float(p01);
            acc.z += __low2float(p23); acc.w += __high2float(p23);
        }
    }
    for (; e < end; e++) {
        int s = sorted_src[e];
        float2 rr = *(const float2*)&h1[(size_t)s * HID + t * 4];
        __half2 p01 = *(const __half2*)&rr.x;
        __half2 p23 = *(const __half2*)&rr.y;
        acc.x += __low2float(p01); acc.y += __high2float(p01);
        acc.z += __low2float(p23); acc.w += __high2float(p23);
    }
    *(float4*)&agg2[(size_t)node * HID + t * 4] = acc;
}

// head: conv2 from agg2 + skip + MLP -> out (8 lanes/node, LDS staged)
__global__ void k_node2head(const float* __restrict__ agg2, const __half* __restrict__ h1,
                            const float* __restrict__ Wl2, const float* __restrict__ bl2,
                            const float* __restrict__ Wr2, const float* __restrict__ Wse2,
                            const float* __restrict__ W3, const float* __restrict__ b3,
                            const float* __restrict__ W4, const float* __restrict__ b4,
                            const float* __restrict__ alpha_p,
                            float* __restrict__ out, int N) {
    __shared__ float sWl2[HID * HID], sWr2[HID * HID], sWse2[HID * HID], sW3[HID * HID];
    __shared__ float sbl2[HID], sb3[HID], sW4[HID];
    __shared__ float sb4, salpha;
    __shared__ float sA[32][HID + 1], sB[32][HID + 1];
    for (int i = threadIdx.x; i < HID * HID; i += blockDim.x) {
        sWl2[i] = Wl2[i]; sWr2[i] = Wr2[i]; sWse2[i] = Wse2[i]; sW3[i] = W3[i];
    }
    for (int i = threadIdx.x; i < HID; i += blockDim.x) { sbl2[i] = bl2[i]; sb3[i] = b3[i]; sW4[i] = W4[i]; }
    if (threadIdx.x == 0) { sb4 = b4[0]; salpha = alpha_p[0]; }
    __syncthreads();

    const int lt = threadIdx.x;
    const int nodeL = lt >> 3;
    const int t = lt & 7;
    const int node = blockIdx.x * 32 + nodeL;
    const bool live = node < N;

    float hvr[4];
    if (live) {
        float4 a = *(const float4*)&agg2[(size_t)node * HID + t * 4];
        float2 ro = *(const float2*)&h1[(size_t)node * HID + t * 4];
        __half2 o01 = *(const __half2*)&ro.x;
        __half2 o23 = *(const __half2*)&ro.y;
        hvr[0] = __low2float(o01); hvr[1] = __high2float(o01);
        hvr[2] = __low2float(o23); hvr[3] = __high2float(o23);
        sA[nodeL][t * 4 + 0] = a.x; sA[nodeL][t * 4 + 1] = a.y;
        sA[nodeL][t * 4 + 2] = a.z; sA[nodeL][t * 4 + 3] = a.w;
        sB[nodeL][t * 4 + 0] = hvr[0]; sB[nodeL][t * 4 + 1] = hvr[1];
        sB[nodeL][t * 4 + 2] = hvr[2]; sB[nodeL][t * 4 + 3] = hvr[3];
    }
    __syncthreads();

    float h2r[4];
    if (live) {
#pragma unroll
        for (int jj = 0; jj < 4; jj++) {
            int j = t * 4 + jj;
            float acc = sbl2[j];
#pragma unroll
            for (int k = 0; k < HID; k++)
                acc += sA[nodeL][k] * sWl2[k * HID + j] + sB[nodeL][k] * sWr2[k * HID + j];
            h2r[jj] = acc > 0.f ? acc : LEAKY * acc;
        }
    }
    __syncthreads();
    if (live) {
#pragma unroll
        for (int jj = 0; jj < 4; jj++) sA[nodeL][t * 4 + jj] = h2r[jj];
    }
    __syncthreads();

    if (live) {
#pragma unroll
        for (int jj = 0; jj < 4; jj++) {
            int j = t * 4 + jj;
            float acc = 0.f;
#pragma unroll
            for (int k = 0; k < HID; k++) acc += sA[nodeL][k] * sWse2[k * HID + j];
            sB[nodeL][j] = salpha * hvr[jj] + acc * SE3NORM;
        }
    }
    __syncthreads();

    float part = 0.f;
#pragma unroll
    for (int jj = 0; jj < 4; jj++) {
        int j = t * 4 + jj;
        float acc = sb3[j];
        if (live) {
#pragma unroll
            for (int k = 0; k < HID; k++) acc += sB[nodeL][k] * sW3[k * HID + j];
        }
        part += (acc > 0.f ? acc : 0.f) * sW4[j];
    }
    part += __shfl_xor(part, 1);
    part += __shfl_xor(part, 2);
    part += __shfl_xor(part, 4);
    if (live && t == 0) out[node] = part + sb4;
}

// fallback direct-gather layer2+head
__global__ void k_node2out(const int* __restrict__ offsets, const int* __restrict__ sorted_src,
                           const __half* __restrict__ h1,
                           const float* __restrict__ Wl2, const float* __restrict__ bl2,
                           const float* __restrict__ Wr2, const float* __restrict__ Wse2,
                           const float* __restrict__ W3, const float* __restrict__ b3,
                           const float* __restrict__ W4, const float* __restrict__ b4,
                           const float* __restrict__ alpha_p,
                           float* __restrict__ out, int N) {
    __shared__ float sWl2[HID * HID], sWr2[HID * HID], sWse2[HID * HID], sW3[HID * HID];
    __shared__ float sbl2[HID], sb3[HID], sW4[HID];
    __shared__ float sb4, salpha;
    __shared__ float sA[32][HID + 1], sB[32][HID + 1];
    for (int i = threadIdx.x; i < HID * HID; i += blockDim.x) {
        sWl2[i] = Wl2[i]; sWr2[i] = Wr2[i]; sWse2[i] = Wse2[i]; sW3[i] = W3[i];
    }
    for (int i = threadIdx.x; i < HID; i += blockDim.x) { sbl2[i] = bl2[i]; sb3[i] = b3[i]; sW4[i] = W4[i]; }
    if (threadIdx.x == 0) { sb4 = b4[0]; salpha = alpha_p[0]; }
    __syncthreads();
    const int lt = threadIdx.x;
    const int nodeL = lt >> 3;
    const int t = lt & 7;
    const int node = blockIdx.x * 32 + nodeL;
    const bool live = node < N;
    float hvr[4];
    if (live) {
        int beg = offsets[node], end = offsets[node + 1];
        float4 acc = make_float4(0.f, 0.f, 0.f, 0.f);
        for (int e = beg; e < end; e++) {
            int s = sorted_src[e];
            float2 rr = *(const float2*)&h1[(size_t)s * HID + t * 4];
            __half2 p01 = *(const __half2*)&rr.x;
            __half2 p23 = *(const __half2*)&rr.y;
            acc.x += __low2float(p01); acc.y += __high2float(p01);
            acc.z += __low2float(p23); acc.w += __high2float(p23);
        }
        float2 ro = *(const float2*)&h1[(size_t)node * HID + t * 4];
        __half2 o01 = *(const __half2*)&ro.x;
        __half2 o23 = *(const __half2*)&ro.y;
        hvr[0] = __low2float(o01); hvr[1] = __high2float(o01);
        hvr[2] = __low2float(o23); hvr[3] = __high2float(o23);
        sA[nodeL][t * 4 + 0] = acc.x; sA[nodeL][t * 4 + 1] = acc.y;
        sA[nodeL][t * 4 + 2] = acc.z; sA[nodeL][t * 4 + 3] = acc.w;
        sB[nodeL][t * 4 + 0] = hvr[0]; sB[nodeL][t * 4 + 1] = hvr[1];
        sB[nodeL][t * 4 + 2] = hvr[2]; sB[nodeL][t * 4 + 3] = hvr[3];
    }
    __syncthreads();
    float h2r[4];
    if (live) {
#pragma unroll
        for (int jj = 0; jj < 4; jj++) {
            int j = t * 4 + jj;
            float acc = sbl2[j];
#pragma unroll
            for (int k = 0; k < HID; k++)
                acc += sA[nodeL][k] * sWl2[k * HID + j] + sB[nodeL][k] * sWr2[k * HID + j];
            h2r[jj] = acc > 0.f ? acc : LEAKY * acc;
        }
    }
    __syncthreads();
    if (live) {
#pragma unroll
        for (int jj = 0; jj < 4; jj++) sA[nodeL][t * 4 + jj] = h2r[jj];
    }
    __syncthreads();
    if (live) {
#pragma unroll
        for (int jj = 0; jj < 4; jj++) {
            int j = t * 4 + jj;
            float acc = 0.f;
#pragma unroll
            for (int k = 0; k < HID; k++) acc += sA[nodeL][k] * sWse2[k * HID + j];
            sB[nodeL][j] = salpha * hvr[jj] + acc * SE3NORM;
        }
    }
    __syncthreads();
    float part = 0.f;
#pragma unroll
    for (int jj = 0; jj < 4; jj++) {
        int j = t * 4 + jj;
        float acc = sb3[j];
        if (live) {
#pragma unroll
            for (int k = 0; k < HID; k++) acc += sB[nodeL][k] * sW3[k * HID + j];
        }
        part += (acc > 0.f ? acc : 0.f) * sW4[j];
    }
    part += __shfl_xor(part, 1);
    part += __shfl_xor(part, 2);
    part += __shfl_xor(part, 4);
    if (live && t == 0) out[node] = part + sb4;
}

extern "C" void kernel_launch(void* const* d_in, const int* in_sizes, int n_in,
                              void* d_out, int out_size, void* d_ws, size_t ws_size,
                              hipStream_t stream) {
    const float* pos  = (const float*)d_in[0];
    const int*   ei   = (const int*)d_in[1];
    const float* Wl1  = (const float*)d_in[2];
    const float* bl1  = (const float*)d_in[3];
    const float* Wr1  = (const float*)d_in[4];
    const float* Wl2  = (const float*)d_in[5];
    const float* bl2  = (const float*)d_in[6];
    const float* Wr2  = (const float*)d_in[7];
    const float* Wse1 = (const float*)d_in[8];
    const float* Wse2 = (const float*)d_in[9];
    const float* W3   = (const float*)d_in[10];
    const float* b3   = (const float*)d_in[11];
    const float* W4   = (const float*)d_in[12];
    const float* b4   = (const float*)d_in[13];
    const float* alp  = (const float*)d_in[14];
    float* out = (float*)d_out;

    const int N = in_sizes[0] / 3;
    const int E = in_sizes[1] / 2;
    const int blk = 256;
    const size_t h1bytes = (size_t)N * HID * sizeof(__half);
    const int rangeSize = (N + RR - 1) / RR;
    const unsigned magic = (unsigned)(((1ULL << 32) + rangeSize - 1) / rangeSize);

    // ---- phased path: coarse dst buckets + 512-bin fine sort ----
    const int B1 = (N + NBK - 1) / NBK;
    const int M2 = B1 * GA;
    const int S2 = (M2 + SCAN_TILE - 1) / SCAN_TILE;
    {
        int* bh         = (int*)d_ws;
        int* bsum       = bh + M2;
        int* region     = bsum + 1024;                      // bucketed[E] then agg2[N*HID]
        size_t regionInts = (size_t)E > (size_t)N * HID ? (size_t)E : (size_t)N * HID;
        int* sorted_src = region + regionInts;
        int* off2       = sorted_src + E;                   // 4N + 1
        uintptr_t hp = ((uintptr_t)(off2 + (size_t)4 * N + 1) + 15) & ~(uintptr_t)15;
        size_t need = (hp - (uintptr_t)d_ws) + h1bytes;
        if (need <= ws_size && S2 <= 1024) {
            int* bucketed = region;
            float* agg2   = (float*)region;
            __half* h1 = (__half*)hp;
            const int chunk = (E + GA - 1) / GA;
            const size_t ldsB = (size_t)B1 * sizeof(int);
            k_bhist<<<GA, 256, ldsB, stream>>>(ei, bh, E, B1, chunk);
            k_scan1<<<S2, 256, 0, stream>>>(bh, bsum, M2);
            k_scan2<<<1, 256, 0, stream>>>(bsum, S2);
            k_scan3<<<(M2 + blk - 1) / blk, blk, 0, stream>>>(bh, bsum, nullptr, M2, 0);
            k_bscatter<<<GA, 256, ldsB, stream>>>(ei, bh, bucketed, E, B1, chunk);
            k_bsort<<<B1, 256, 0, stream>>>(bh, bucketed, sorted_src, off2, E, N, B1, magic);
            k_node1<<<(N + blk - 1) / blk, blk, 0, stream>>>(off2, sorted_src, pos,
                                                             Wl1, bl1, Wr1, Wse1, h1, N, 4, 4);
            const int agrid = ((N * 8) + blk - 1) / blk;
            for (int r = 0; r < RR; r++)
                k_node2agg<<<agrid, blk, 0, stream>>>(off2, sorted_src, h1, agg2, N, r);
            k_node2head<<<(N + 31) / 32, 256, 0, stream>>>(agg2, h1, Wl2, bl2, Wr2, Wse2,
                                                           W3, b3, W4, b4, alp, out, N);
            return;
        }
    }

    // ---- fallback: global-atomic CSR build + direct gather ----
    const int M = N + 1;
    const int B = (M + SCAN_TILE - 1) / SCAN_TILE;
    int* hist       = (int*)d_ws;
    int* bsum       = hist + M;
    int* sorted_src = bsum + 1024;
    int* aux        = sorted_src + E;          // rank[E]
    uintptr_t hpA = ((uintptr_t)(aux + E) + 15) & ~(uintptr_t)15;
    __half* h1 = (__half*)hpA;

    hipMemsetAsync(hist, 0, (size_t)M * sizeof(int), stream);
    const int egrid4 = (E / 4 + blk) / blk;
    k_hist_rank<<<egrid4, blk, 0, stream>>>(ei, hist, aux, E);
    k_scan1<<<B, 256, 0, stream>>>(hist, bsum, M);
    k_scan2<<<1, 256, 0, stream>>>(bsum, B);
    k_scan3<<<(M + blk - 1) / blk, blk, 0, stream>>>(hist, bsum, nullptr, M, N);
    int* offs = hist;
    k_scatter_rank<<<egrid4, blk, 0, stream>>>(ei, offs, aux, sorted_src, E);
    k_node1<<<(N + blk - 1) / blk, blk, 0, stream>>>(offs, sorted_src, pos, Wl1, bl1, Wr1, Wse1, h1, N, 1, 1);
    k_node2out<<<(N + 31) / 32, 256, 0, stream>>>(offs, sorted_src, h1, Wl2, bl2, Wr2, Wse2,
                                                  W3, b3, W4, b4, alp, out, N);
}